// Round 3
// baseline (1435.572 us; speedup 1.0000x reference)
//
#include <hip/hip_runtime.h>
#include <math.h>

#define NB1 10000
#define NB2 10000
#define DD  128
#define NV  4          // steerer order
#define B1P 10016      // rows padded to multiple of 32

#define BM  32         // desc1 rows per block
#define BN  128        // desc2 cols per tile
#define KC  32         // K chunk in LDS
#define LDA 132        // padded LDS stride (floats); 132*4=528 bytes, 16B-aligned
#define NCHUNK 4       // j-range split for occupancy

#define SROWS 16

// ---------------- small prep kernels ----------------

__global__ void gt_kernel(const float* __restrict__ G, float* __restrict__ GT) {
    int idx = blockIdx.x * 256 + threadIdx.x;
    if (idx < DD * DD) {
        int c = idx / DD, f = idx % DD;
        GT[idx] = G[f * DD + c];   // GT[c][f] = G[f][c]
    }
}

// copy desc1 -> Ast version 0 (zero-pad rows >= NB1), compute n1[i][0]
__global__ void init1_kernel(const float* __restrict__ desc1,
                             float* __restrict__ Ast, float* __restrict__ n1) {
    int i = blockIdx.x;
    int t = threadIdx.x;   // 128
    float v = (i < NB1) ? desc1[i * DD + t] : 0.f;
    Ast[(i * NV) * DD + t] = v;
    float s = v * v;
    for (int off = 32; off; off >>= 1) s += __shfl_down(s, off);
    __shared__ float p[2];
    if ((t & 63) == 0) p[t >> 6] = s;
    __syncthreads();
    if (t == 0) n1[i * NV] = p[0] + p[1];
}

__global__ void norm2_kernel(const float* __restrict__ desc2, float* __restrict__ n2) {
    int j = blockIdx.x;
    int t = threadIdx.x;   // 128
    float v = desc2[j * DD + t];
    float s = v * v;
    for (int off = 32; off; off >>= 1) s += __shfl_down(s, off);
    __shared__ float p[2];
    if ((t & 63) == 0) p[t >> 6] = s;
    __syncthreads();
    if (t == 0) n2[j] = p[0] + p[1];
}

// Ast[i][k][:] = Ast[i][k-1][:] @ G^T   (out[f] = sum_c src[c] * G[f][c] = sum_c src[c] * GT[c][f])
__global__ void steer_kernel(float* __restrict__ Ast, const float* __restrict__ GT,
                             float* __restrict__ n1, int k) {
    __shared__ float src[SROWS][DD];
    int i0 = blockIdx.x * SROWS;
    int t = threadIdx.x;   // 128
    for (int r = 0; r < SROWS; ++r)
        src[r][t] = Ast[((i0 + r) * NV + (k - 1)) * DD + t];
    __syncthreads();
    float out[SROWS];
#pragma unroll
    for (int r = 0; r < SROWS; ++r) out[r] = 0.f;
    for (int c = 0; c < DD; ++c) {
        float g = GT[c * DD + t];
#pragma unroll
        for (int r = 0; r < SROWS; ++r) out[r] = fmaf(src[r][c], g, out[r]);
    }
    __shared__ float p2[SROWS][2];
    for (int r = 0; r < SROWS; ++r) {
        Ast[((i0 + r) * NV + k) * DD + t] = out[r];
        float s = out[r] * out[r];
        for (int off = 32; off; off >>= 1) s += __shfl_down(s, off);
        if ((t & 63) == 0) p2[r][t >> 6] = s;
    }
    __syncthreads();
    if (t < SROWS) n1[(i0 + t) * NV + k] = p2[t][0] + p2[t][1];
}

// ---------------- main fused match kernel ----------------
// A-rows = BM*NV = 128 (version-interleaved). Thread (tx,ty) in 16x16 grid:
//   rows: {ty*4+m} (i0+ty) and {64+ty*4+m} (i0+16+ty), m = version
//   cols: {tx*4+e} and {64+tx*4+e}

__global__ __launch_bounds__(256) void match_kernel(
    const float* __restrict__ Ast, const float* __restrict__ desc2,
    const float* __restrict__ n1, const float* __restrict__ n2,
    float* __restrict__ pbest, int* __restrict__ pidx) {
    __shared__ float As[KC][LDA];
    __shared__ float Bs[KC][LDA];
    const int bi = blockIdx.x, ch = blockIdx.y;
    const int i0 = bi * BM;
    const int t = threadIdx.x;
    const int tx = t & 15, ty = t >> 4;
    const int NT = (NB2 + BN - 1) / BN;                 // 79 j-tiles total
    const int jt0 = (ch * NT) / NCHUNK;
    const int jt1 = ((ch + 1) * NT) / NCHUNK;

    float n1r[2][4];
#pragma unroll
    for (int m = 0; m < 4; ++m) {
        n1r[0][m] = n1[(i0 + ty) * NV + m];
        n1r[1][m] = n1[(i0 + 16 + ty) * NV + m];
    }

    float best0 = 3.4e38f, best1 = 3.4e38f;
    int bj0 = 0, bj1 = 0;

    for (int jt = jt0; jt < jt1; ++jt) {
        const int j0 = jt * BN;
        float acc[2][4][8];
#pragma unroll
        for (int mi = 0; mi < 2; ++mi)
#pragma unroll
            for (int m = 0; m < 4; ++m)
#pragma unroll
                for (int n = 0; n < 8; ++n) acc[mi][m][n] = 0.f;

        for (int kc = 0; kc < DD; kc += KC) {
            __syncthreads();   // protect LDS reuse
#pragma unroll
            for (int s = 0; s < 4; ++s) {
                int q = t + 256 * s;
                int r = q >> 3, c4 = q & 7;
                float4 va = *reinterpret_cast<const float4*>(
                    &Ast[(i0 * NV + r) * DD + kc + c4 * 4]);
                As[c4 * 4 + 0][r] = va.x;
                As[c4 * 4 + 1][r] = va.y;
                As[c4 * 4 + 2][r] = va.z;
                As[c4 * 4 + 3][r] = va.w;
                int j = j0 + r;
                float4 vb = make_float4(0.f, 0.f, 0.f, 0.f);
                if (j < NB2)
                    vb = *reinterpret_cast<const float4*>(&desc2[j * DD + kc + c4 * 4]);
                Bs[c4 * 4 + 0][r] = vb.x;
                Bs[c4 * 4 + 1][r] = vb.y;
                Bs[c4 * 4 + 2][r] = vb.z;
                Bs[c4 * 4 + 3][r] = vb.w;
            }
            __syncthreads();
#pragma unroll 8
            for (int kk = 0; kk < KC; ++kk) {
                float4 a0 = *reinterpret_cast<const float4*>(&As[kk][ty * 4]);
                float4 a1 = *reinterpret_cast<const float4*>(&As[kk][64 + ty * 4]);
                float4 b0 = *reinterpret_cast<const float4*>(&Bs[kk][tx * 4]);
                float4 b1 = *reinterpret_cast<const float4*>(&Bs[kk][64 + tx * 4]);
                float am[2][4] = {{a0.x, a0.y, a0.z, a0.w}, {a1.x, a1.y, a1.z, a1.w}};
                float bn[2][4] = {{b0.x, b0.y, b0.z, b0.w}, {b1.x, b1.y, b1.z, b1.w}};
#pragma unroll
                for (int mi = 0; mi < 2; ++mi)
#pragma unroll
                    for (int m = 0; m < 4; ++m)
#pragma unroll
                        for (int g = 0; g < 2; ++g)
#pragma unroll
                            for (int e = 0; e < 4; ++e)
                                acc[mi][m][g * 4 + e] =
                                    fmaf(am[mi][m], bn[g][e], acc[mi][m][g * 4 + e]);
            }
        }
        // epilogue: dist = sqrt(clip(n1+n2-2dot)), min over versions, running argmin
#pragma unroll
        for (int g = 0; g < 2; ++g)
#pragma unroll
            for (int e = 0; e < 4; ++e) {
                int j = j0 + g * 64 + tx * 4 + e;
                if (j < NB2) {
                    float nn = n2[j];
                    float d0 = fmaf(-2.f, acc[0][0][g * 4 + e], n1r[0][0] + nn);
                    float d1 = fmaf(-2.f, acc[0][1][g * 4 + e], n1r[0][1] + nn);
                    float d2 = fmaf(-2.f, acc[0][2][g * 4 + e], n1r[0][2] + nn);
                    float d3 = fmaf(-2.f, acc[0][3][g * 4 + e], n1r[0][3] + nn);
                    float dmin = fminf(fminf(d0, d1), fminf(d2, d3));
                    float v = sqrtf(fmaxf(dmin, 0.f));
                    if (v < best0) { best0 = v; bj0 = j; }
                    d0 = fmaf(-2.f, acc[1][0][g * 4 + e], n1r[1][0] + nn);
                    d1 = fmaf(-2.f, acc[1][1][g * 4 + e], n1r[1][1] + nn);
                    d2 = fmaf(-2.f, acc[1][2][g * 4 + e], n1r[1][2] + nn);
                    d3 = fmaf(-2.f, acc[1][3][g * 4 + e], n1r[1][3] + nn);
                    dmin = fminf(fminf(d0, d1), fminf(d2, d3));
                    v = sqrtf(fmaxf(dmin, 0.f));
                    if (v < best1) { best1 = v; bj1 = j; }
                }
            }
    }

    // reduce (val, idx) across the 16 tx lanes (contiguous 16-lane groups in a wave)
#pragma unroll
    for (int off = 1; off < 16; off <<= 1) {
        float ov = __shfl_xor(best0, off);
        int oj = __shfl_xor(bj0, off);
        if (ov < best0 || (ov == best0 && oj < bj0)) { best0 = ov; bj0 = oj; }
        ov = __shfl_xor(best1, off);
        oj = __shfl_xor(bj1, off);
        if (ov < best1 || (ov == best1 && oj < bj1)) { best1 = ov; bj1 = oj; }
    }
    if (tx == 0) {
        pbest[ch * B1P + i0 + ty] = best0;
        pidx [ch * B1P + i0 + ty] = bj0;
        pbest[ch * B1P + i0 + 16 + ty] = best1;
        pidx [ch * B1P + i0 + 16 + ty] = bj1;
    }
}

__global__ void final_kernel(const float* __restrict__ pbest, const int* __restrict__ pidx,
                             float* __restrict__ out) {
    int i = blockIdx.x * 256 + threadIdx.x;
    if (i < NB1) {
        float bv = pbest[i];
        int bj = pidx[i];
#pragma unroll
        for (int c = 1; c < NCHUNK; ++c) {
            float v = pbest[c * B1P + i];
            int j = pidx[c * B1P + i];
            if (v < bv || (v == bv && j < bj)) { bv = v; bj = j; }
        }
        out[i] = bv;                       // match_dists (10000,1)
        out[NB1 + 2 * i] = (float)i;       // matches_idxs[:,0]
        out[NB1 + 2 * i + 1] = (float)bj;  // matches_idxs[:,1]
    }
}

// ---------------- launch ----------------

extern "C" void kernel_launch(void* const* d_in, const int* in_sizes, int n_in,
                              void* d_out, int out_size, void* d_ws, size_t ws_size,
                              hipStream_t stream) {
    const float* desc1 = (const float*)d_in[0];
    const float* desc2 = (const float*)d_in[1];
    const float* G     = (const float*)d_in[2];

    float* ws    = (float*)d_ws;
    float* Ast   = ws;                                   // B1P*NV*DD
    float* n1    = Ast + (size_t)B1P * NV * DD;          // B1P*NV
    float* n2    = n1 + (size_t)B1P * NV;                // NB2
    float* GT    = n2 + NB2;                             // DD*DD
    float* pbest = GT + DD * DD;                         // NCHUNK*B1P
    int*   pidx  = (int*)(pbest + NCHUNK * B1P);         // NCHUNK*B1P
    float* out   = (float*)d_out;

    hipLaunchKernelGGL(gt_kernel, dim3((DD * DD + 255) / 256), dim3(256), 0, stream, G, GT);
    hipLaunchKernelGGL(init1_kernel, dim3(B1P), dim3(DD), 0, stream, desc1, Ast, n1);
    hipLaunchKernelGGL(norm2_kernel, dim3(NB2), dim3(DD), 0, stream, desc2, n2);
    for (int k = 1; k < NV; ++k)
        hipLaunchKernelGGL(steer_kernel, dim3(B1P / SROWS), dim3(DD), 0, stream, Ast, GT, n1, k);
    hipLaunchKernelGGL(match_kernel, dim3((NB1 + BM - 1) / BM, NCHUNK), dim3(256), 0, stream,
                       Ast, desc2, n1, n2, pbest, pidx);
    hipLaunchKernelGGL(final_kernel, dim3((NB1 + 255) / 256), dim3(256), 0, stream,
                       pbest, pidx, out);
}

// Round 6
// 529.671 us; speedup vs baseline: 2.7103x; 2.7103x over previous
//
#include <hip/hip_runtime.h>
#include <hip/hip_fp16.h>
#include <math.h>

#define NB1 10000
#define NB2 10000
#define DD  128
#define NV  4
#define B1P 10016            // desc1 rows padded to 32
#define B1R (B1P * NV)       // 40064 A-rows (313 * 128)
#define NB2P 10112           // 79 * 128 B rows
#define NJT 79               // j-tiles of 128
#define MB  128              // A-rows per block
#define BN  128
#define NCHUNK 4
#define SROWS 16
#define SCALE 64.0f          // descriptor pre-scale; acc = 4096*dot, epilogue applies -2/4096

typedef _Float16 f16x8 __attribute__((ext_vector_type(8)));
typedef __attribute__((ext_vector_type(16))) float f32x16;

__device__ __forceinline__ void gload_lds16(const void* g, void* l) {
    __builtin_amdgcn_global_load_lds(
        (const __attribute__((address_space(1))) void*)g,
        (__attribute__((address_space(3))) void*)l, 16, 0, 0);
}
__device__ __forceinline__ f32x16 mfma16(f16x8 a, f16x8 b, f32x16 c) {
    return __builtin_amdgcn_mfma_f32_32x32x16_f16(a, b, c, 0, 0, 0);
}
// encode x*SCALE as f16 hi/lo bit patterns
__device__ __forceinline__ void enc(float x, unsigned short* hb, unsigned short* lb) {
    float xs = SCALE * x;
    __half hh = __float2half_rn(xs);
    __half hl = __float2half_rn(xs - __half2float(hh));
    *hb = __half_as_ushort(hh);
    *lb = __half_as_ushort(hl);
}

// ---------------- prep ----------------

__global__ void gt_kernel(const float* __restrict__ G, float* __restrict__ GT) {
    int idx = blockIdx.x * 256 + threadIdx.x;
    if (idx < DD * DD) {
        int c = idx / DD, f = idx % DD;
        GT[idx] = G[f * DD + c];
    }
}

// desc1 row i -> A2 row i*4 (f16 hi|lo of SCALE*x), F0 row i (fp32 chain), n1[i*4]
__global__ void prep1_kernel(const float* __restrict__ desc1,
                             unsigned short* __restrict__ A2, float* __restrict__ F0,
                             float* __restrict__ n1) {
    int i = blockIdx.x;           // 0..B1P-1
    int t = threadIdx.x;          // 128
    float x = (i < NB1) ? desc1[i * DD + t] : 0.f;
    F0[(size_t)i * DD + t] = x;
    unsigned short hb, lb;
    enc(x, &hb, &lb);
    size_t base = (size_t)(i * NV) * 256;
    A2[base + t] = hb;
    A2[base + 128 + t] = lb;
    float s = x * x;
    for (int off = 32; off; off >>= 1) s += __shfl_down(s, off);
    __shared__ float p[2];
    if ((t & 63) == 0) p[t >> 6] = s;
    __syncthreads();
    if (t == 0) n1[i * NV] = p[0] + p[1];
}

// desc2 row j -> B2 (f16 hi|lo), n2[j] (pad rows: zeros, n2=1e30)
__global__ void prep2_kernel(const float* __restrict__ desc2,
                             unsigned short* __restrict__ B2, float* __restrict__ n2) {
    int j = blockIdx.x;           // 0..NB2P-1
    int t = threadIdx.x;          // 128
    float x = (j < NB2) ? desc2[j * DD + t] : 0.f;
    unsigned short hb, lb;
    enc(x, &hb, &lb);
    size_t base = (size_t)j * 256;
    B2[base + t] = hb;
    B2[base + 128 + t] = lb;
    float s = x * x;
    for (int off = 32; off; off >>= 1) s += __shfl_down(s, off);
    __shared__ float p[2];
    if ((t & 63) == 0) p[t >> 6] = s;
    __syncthreads();
    if (t == 0) n2[j] = (j < NB2) ? (p[0] + p[1]) : 1e30f;
}

// version k from fp32 version k-1 (IN-PLACE safe: each block reads only its own
// 16 rows into LDS before overwriting them). Writes fp32 chain + f16 pair + n1.
__global__ void steer_kernel(float* __restrict__ F, unsigned short* __restrict__ A2,
                             const float* __restrict__ GT, float* __restrict__ n1, int k) {
    __shared__ float src[SROWS][DD];
    int i0 = blockIdx.x * SROWS;
    int t = threadIdx.x;          // 128
    for (int r = 0; r < SROWS; ++r)
        src[r][t] = F[(size_t)(i0 + r) * DD + t];
    __syncthreads();
    float out[SROWS];
#pragma unroll
    for (int r = 0; r < SROWS; ++r) out[r] = 0.f;
    for (int c = 0; c < DD; ++c) {
        float g = GT[c * DD + t];
#pragma unroll
        for (int r = 0; r < SROWS; ++r) out[r] = fmaf(src[r][c], g, out[r]);
    }
    __shared__ float p2[SROWS][2];
    for (int r = 0; r < SROWS; ++r) {
        F[(size_t)(i0 + r) * DD + t] = out[r];
        unsigned short hb, lb;
        enc(out[r], &hb, &lb);
        size_t base = (size_t)((i0 + r) * NV + k) * 256;
        A2[base + t] = hb;
        A2[base + 128 + t] = lb;
        float s = out[r] * out[r];
        for (int off = 32; off; off >>= 1) s += __shfl_down(s, off);
        if ((t & 63) == 0) p2[r][t >> 6] = s;
    }
    __syncthreads();
    if (t < SROWS) n1[(i0 + t) * NV + k] = p2[t][0] + p2[t][1];
}

// ---------------- fused MFMA match kernel ----------------
// M=128 A-rows (version-interleaved), BN=128 j per tile, K=384 eff (AhiBhi|AloBhi|AhiBlo).
// A persistent in LDS (64KB, fragment-ready), B streamed (16KB). 4 waves 2x2.
// LDS chunk layout (1KB each = 64 lanes x 16B): A chunk ((aks*4+k16)*4+mf), B chunk (k16*4+nf).

__global__ __launch_bounds__(256) void match_kernel(
    const unsigned short* __restrict__ A2, const unsigned short* __restrict__ B2,
    const float* __restrict__ n1, const float* __restrict__ n2,
    float* __restrict__ pb, int* __restrict__ pj) {
    __shared__ __align__(16) char LDS[80 * 1024];   // A: 0..64KB, B: 64KB..80KB
    const int t = threadIdx.x;
    const int l = t & 63, w = t >> 6;
    const int wm = w >> 1, wn = w & 1;
    const int c5 = l & 31, h = l >> 5;
    const int bi = blockIdx.x, ch = blockIdx.y;
    const int R0 = bi * MB;

    // ---- stage A once: 64 chunks, 16 per wave ----
#pragma unroll
    for (int q = 0; q < 16; ++q) {
        int chunk = w * 16 + q;
        int aks = chunk >> 4, k16 = (chunk >> 2) & 3, mf = chunk & 3;
        int row = R0 + mf * 32 + c5;
        int col = aks * 64 + k16 * 16 + h * 8;    // element in 256-wide A2 row
        gload_lds16(A2 + (size_t)row * 256 + col, LDS + chunk * 1024 + l * 16);
    }

    // n1 regs: A-row = R0 + (wm*2+a)*32 + 8*rq + 4*h + m  (m contiguous -> float4)
    float4 n1r[2][4];
#pragma unroll
    for (int a = 0; a < 2; ++a)
#pragma unroll
        for (int rq = 0; rq < 4; ++rq)
            n1r[a][rq] = *(const float4*)&n1[R0 + (wm * 2 + a) * 32 + 8 * rq + 4 * h];

    float best[2][4];
    int bj[2][4];
#pragma unroll
    for (int a = 0; a < 2; ++a)
#pragma unroll
        for (int rq = 0; rq < 4; ++rq) { best[a][rq] = 3.4e38f; bj[a][rq] = 0; }

    const int jt0 = (ch * NJT) / NCHUNK;
    const int jt1 = ((ch + 1) * NJT) / NCHUNK;

    for (int jt = jt0; jt < jt1; ++jt) {
        const int j0 = jt * BN;
        f32x16 acc[2][2];
#pragma unroll
        for (int a = 0; a < 2; ++a)
#pragma unroll
            for (int b = 0; b < 2; ++b)
#pragma unroll
                for (int e = 0; e < 16; ++e) acc[a][b][e] = 0.f;

        // st order: seg0=Ahi*Bhi, seg1=Alo*Bhi (B-hi reused while hot), seg2=Ahi*Blo
#pragma unroll
        for (int st = 0; st < 6; ++st) {
            const int seg = st >> 1;
            const int aks = ((seg == 1) ? 2 : 0) + (st & 1);
            const int segB = (seg == 2) ? 128 : 0;
            const int kc = (st & 1) * 64;
            __syncthreads();   // previous reads of B done (also covers A-stage on st=0)
#pragma unroll
            for (int q = 0; q < 4; ++q) {
                int chunk = w * 4 + q;
                int k16 = chunk >> 2, nf = chunk & 3;
                int jrow = j0 + nf * 32 + c5;
                int col = segB + kc + k16 * 16 + h * 8;
                gload_lds16(B2 + (size_t)jrow * 256 + col,
                            LDS + 65536 + chunk * 1024 + l * 16);
            }
            __syncthreads();   // drains vmcnt (global_load_lds) before reads
#pragma unroll
            for (int k16 = 0; k16 < 4; ++k16) {
                f16x8 a0 = *(const f16x8*)(LDS + (((aks * 4 + k16) * 4 + wm * 2 + 0) * 1024) + l * 16);
                f16x8 a1 = *(const f16x8*)(LDS + (((aks * 4 + k16) * 4 + wm * 2 + 1) * 1024) + l * 16);
                f16x8 b0 = *(const f16x8*)(LDS + 65536 + ((k16 * 4 + wn * 2 + 0) * 1024) + l * 16);
                f16x8 b1 = *(const f16x8*)(LDS + 65536 + ((k16 * 4 + wn * 2 + 1) * 1024) + l * 16);
                acc[0][0] = mfma16(a0, b0, acc[0][0]);
                acc[0][1] = mfma16(a0, b1, acc[0][1]);
                acc[1][0] = mfma16(a1, b0, acc[1][0]);
                acc[1][1] = mfma16(a1, b1, acc[1][1]);
            }
        }

        // epilogue: e_m = n1_m - 2*dot (dot = acc/4096) ; min over 4 versions ; + n2 ; argmin
        float nn0 = n2[j0 + wn * 64 + c5];
        float nn1 = n2[j0 + wn * 64 + 32 + c5];
#pragma unroll
        for (int a = 0; a < 2; ++a)
#pragma unroll
            for (int b = 0; b < 2; ++b) {
                float nn = b ? nn1 : nn0;
                int j = j0 + wn * 64 + b * 32 + c5;
#pragma unroll
                for (int rq = 0; rq < 4; ++rq) {
                    float e0 = fmaf(-0.00048828125f, acc[a][b][4 * rq + 0], n1r[a][rq].x);
                    float e1 = fmaf(-0.00048828125f, acc[a][b][4 * rq + 1], n1r[a][rq].y);
                    float e2 = fmaf(-0.00048828125f, acc[a][b][4 * rq + 2], n1r[a][rq].z);
                    float e3 = fmaf(-0.00048828125f, acc[a][b][4 * rq + 3], n1r[a][rq].w);
                    float d = fminf(fminf(e0, e1), fminf(e2, e3)) + nn;
                    if (d < best[a][rq]) { best[a][rq] = d; bj[a][rq] = j; }
                }
            }
    }

    // reduce across the 32 column-lanes (offsets < 32 stay within same h)
#pragma unroll
    for (int off = 1; off < 32; off <<= 1) {
#pragma unroll
        for (int a = 0; a < 2; ++a)
#pragma unroll
            for (int rq = 0; rq < 4; ++rq) {
                float ov = __shfl_xor(best[a][rq], off);
                int oj = __shfl_xor(bj[a][rq], off);
                if (ov < best[a][rq] || (ov == best[a][rq] && oj < bj[a][rq])) {
                    best[a][rq] = ov; bj[a][rq] = oj;
                }
            }
    }
    if (c5 == 0) {
        int slot = ch * 2 + wn;
#pragma unroll
        for (int a = 0; a < 2; ++a)
#pragma unroll
            for (int rq = 0; rq < 4; ++rq) {
                int i = bi * 32 + (wm * 2 + a) * 8 + 2 * rq + h;
                pb[slot * B1P + i] = best[a][rq];
                pj[slot * B1P + i] = bj[a][rq];
            }
    }
}

__global__ void final_kernel(const float* __restrict__ pb, const int* __restrict__ pj,
                             float* __restrict__ out) {
    int i = blockIdx.x * 256 + threadIdx.x;
    if (i < NB1) {
        float bv = 3.4e38f;
        int bj = 0;
#pragma unroll
        for (int s = 0; s < 2 * NCHUNK; ++s) {
            float v = pb[s * B1P + i];
            int j = pj[s * B1P + i];
            if (v < bv || (v == bv && j < bj)) { bv = v; bj = j; }
        }
        out[i] = sqrtf(fmaxf(bv, 0.f));
        out[NB1 + 2 * i] = (float)i;
        out[NB1 + 2 * i + 1] = (float)bj;
    }
}

// ---------------- launch ----------------

extern "C" void kernel_launch(void* const* d_in, const int* in_sizes, int n_in,
                              void* d_out, int out_size, void* d_ws, size_t ws_size,
                              hipStream_t stream) {
    const float* desc1 = (const float*)d_in[0];
    const float* desc2 = (const float*)d_in[1];
    const float* G     = (const float*)d_in[2];

    unsigned short* A2 = (unsigned short*)d_ws;              // B1R*256 ushort
    unsigned short* B2 = A2 + (size_t)B1R * 256;             // NB2P*256 ushort
    float* F0 = (float*)(B2 + (size_t)NB2P * 256);           // B1P*DD fp32 chain (in-place)
    float* GT = F0 + (size_t)B1P * DD;                       // DD*DD
    float* n1 = GT + DD * DD;                                // B1R
    float* n2 = n1 + B1R;                                    // NB2P
    float* pb = n2 + NB2P;                                   // 2*NCHUNK*B1P
    int*   pj = (int*)(pb + 2 * NCHUNK * B1P);               // 2*NCHUNK*B1P
    float* out = (float*)d_out;

    hipLaunchKernelGGL(gt_kernel, dim3((DD * DD + 255) / 256), dim3(256), 0, stream, G, GT);
    hipLaunchKernelGGL(prep1_kernel, dim3(B1P), dim3(DD), 0, stream, desc1, A2, F0, n1);
    hipLaunchKernelGGL(prep2_kernel, dim3(NB2P), dim3(DD), 0, stream, desc2, B2, n2);
    for (int k = 1; k < NV; ++k)
        hipLaunchKernelGGL(steer_kernel, dim3(B1P / SROWS), dim3(DD), 0, stream,
                           F0, A2, GT, n1, k);
    hipLaunchKernelGGL(match_kernel, dim3(B1R / MB, NCHUNK), dim3(256), 0, stream,
                       A2, B2, n1, n2, pb, pj);
    hipLaunchKernelGGL(final_kernel, dim3((NB1 + 255) / 256), dim3(256), 0, stream,
                       pb, pj, out);
}